// Round 4
// baseline (3437.021 us; speedup 1.0000x reference)
//
#include <hip/hip_runtime.h>

// Problem constants: B=32, S=1024, I=1024, H=1024, W is (H, I+H)
#define B_ 32
#define S_ 1024
#define H_ 1024
#define NWG 64            // 2 batch-groups x 32 col-groups
#define EXN32 (32 * 1024) // one exchange buffer: 32 x 1024 packed u32 cells

typedef float f32x4 __attribute__((ext_vector_type(4)));
typedef short bf16x8 __attribute__((ext_vector_type(8)));
typedef unsigned int u32x4 __attribute__((ext_vector_type(4)));
typedef unsigned short u16;

__device__ __forceinline__ short f2bf(float f) {
  union { float f; unsigned u; } v; v.f = f;
  unsigned r = v.u + 0x7FFFu + ((v.u >> 16) & 1u);
  return (short)(r >> 16);
}

__device__ __forceinline__ void stg_coh_u32(unsigned* p, unsigned v) {
  asm volatile("global_store_dword %0, %1, off sc0 sc1"
               :: "v"(p), "v"(v) : "memory");
}

// Build one bf16x8 A-fragment from 8 packed cells (h in high 16 of each dword)
__device__ __forceinline__ bf16x8 mk_frag(u32x4 lo, u32x4 hi) {
  union { unsigned u[4]; bf16x8 v; } c;
  c.u[0] = (lo[0] >> 16) | (lo[1] & 0xffff0000u);
  c.u[1] = (lo[2] >> 16) | (lo[3] & 0xffff0000u);
  c.u[2] = (hi[0] >> 16) | (hi[1] & 0xffff0000u);
  c.u[3] = (hi[2] >> 16) | (hi[3] & 0xffff0000u);
  return c.v;
}

// ============================================================================
// Kernel 1: xz GEMM (R1-verified, unchanged).
// ============================================================================
__global__ __launch_bounds__(256) void xz_gemm(
    const float* __restrict__ X, const float* __restrict__ W,
    const float* __restrict__ bias, float* __restrict__ C) {
  __shared__ short As[128][40];
  __shared__ short Bs[128][40];
  const int tid  = threadIdx.x;
  const int lane = tid & 63, wave = tid >> 6;
  const int m0 = blockIdx.y * 128, n0 = blockIdx.x * 128;
  const int wm = (wave >> 1) * 64, wn = (wave & 1) * 64;
  const int jl = lane & 15, kq = lane >> 4;
  const int sr = tid >> 2, skg = (tid & 3) * 8;

  f32x4 zero4 = {0.f, 0.f, 0.f, 0.f};
  f32x4 acc[4][4];
  #pragma unroll
  for (int mi = 0; mi < 4; ++mi)
    #pragma unroll
    for (int ni = 0; ni < 4; ++ni) acc[mi][ni] = zero4;

  for (int k0 = 0; k0 < 1024; k0 += 32) {
    #pragma unroll
    for (int rr = 0; rr < 2; ++rr) {
      int row = sr + rr * 64;
      const float* pa = X + (size_t)(m0 + row) * 1024 + k0 + skg;
      f32x4 a0 = *(const f32x4*)pa;
      f32x4 a1 = *(const f32x4*)(pa + 4);
      bf16x8 pk;
      #pragma unroll
      for (int e = 0; e < 4; ++e) { pk[e] = f2bf(a0[e]); pk[e + 4] = f2bf(a1[e]); }
      *(bf16x8*)&As[row][skg] = pk;
      const float* pb = W + (size_t)(n0 + row) * 2048 + 1024 + k0 + skg;
      f32x4 b0 = *(const f32x4*)pb;
      f32x4 b1 = *(const f32x4*)(pb + 4);
      bf16x8 qk;
      #pragma unroll
      for (int e = 0; e < 4; ++e) { qk[e] = f2bf(b0[e]); qk[e + 4] = f2bf(b1[e]); }
      *(bf16x8*)&Bs[row][skg] = qk;
    }
    __syncthreads();
    bf16x8 af[4], bfv[4];
    #pragma unroll
    for (int mi = 0; mi < 4; ++mi) af[mi] = *(const bf16x8*)&As[wm + mi * 16 + jl][kq * 8];
    #pragma unroll
    for (int ni = 0; ni < 4; ++ni) bfv[ni] = *(const bf16x8*)&Bs[wn + ni * 16 + jl][kq * 8];
    #pragma unroll
    for (int mi = 0; mi < 4; ++mi)
      #pragma unroll
      for (int ni = 0; ni < 4; ++ni)
        acc[mi][ni] = __builtin_amdgcn_mfma_f32_16x16x32_bf16(af[mi], bfv[ni], acc[mi][ni], 0, 0, 0);
    __syncthreads();
  }
  #pragma unroll
  for (int ni = 0; ni < 4; ++ni) {
    int col = n0 + wn + ni * 16 + jl;
    float bv = bias[col];
    #pragma unroll
    for (int mi = 0; mi < 4; ++mi) {
      int rbase = m0 + wm + mi * 16 + kq * 4;
      #pragma unroll
      for (int r = 0; r < 4; ++r)
        C[(size_t)(rbase + r) * 1024 + col] = acc[mi][ni][r] + bv;
    }
  }
}

// ============================================================================
// Kernel 2: recurrence with SELF-VALIDATING exchange.
//   Cell = (bf16(h)<<16) | tag, tag = version (h_v has tag v+1), ping-pong by
//   parity v&1. Consumers spin on the data loads themselves; no flags, no
//   producer-side drain, one __syncthreads per step (zred parity-dbuf'd).
//   WAR safe: publishing tag t+2 (parity p) requires having consumed tag t+1
//   from all 32 peers of the bg, which implies all their reads of parity p
//   (tag t) finished.
// ============================================================================
__global__ __launch_bounds__(512) void lstm_rec(
    const float* __restrict__ W, const float* __restrict__ h0,
    const float* __restrict__ c0, float* __restrict__ out,
    unsigned* __restrict__ exch) {
  __shared__ short Whs[32 * 1024];          // 64 KB bf16, XOR-swizzled
  __shared__ float zred[2][8][2][64][5];    // 40 KB, parity-dbuf, pad 5
  const int tid  = threadIdx.x;
  const int lane = tid & 63, wave = tid >> 6;
  const int jl = lane & 15, kq = lane >> 4;
  const int bg = blockIdx.x >> 5;
  const int cg = blockIdx.x & 31;

  // --- stage Wh[32cg + j][k] -> LDS bf16, swizzled
  {
    int j  = tid >> 4;
    int g0 = (tid & 15) * 8;
    const float* wrow = W + (size_t)(cg * 32 + j) * 2048;   // Wh = W[:, :1024]
    #pragma unroll
    for (int g = 0; g < 8; ++g) {
      int grp = g0 + g;
      const float* p = wrow + grp * 8;
      f32x4 a0 = *(const f32x4*)p;
      f32x4 a1 = *(const f32x4*)(p + 4);
      bf16x8 pk;
      #pragma unroll
      for (int e = 0; e < 4; ++e) { pk[e] = f2bf(a0[e]); pk[e + 4] = f2bf(a1[e]); }
      *(bf16x8*)&Whs[(j * 128 + (grp ^ (j & 7))) * 8] = pk;
    }
  }

  // --- owner thread (bp,cp); publish h0 with tag 1 into parity 0
  const int bp  = tid >> 5;
  const int cp  = tid & 31;
  const int b   = bg * 16 + bp;
  const int col = cg * 32 + cp;
  float cst  = c0[b * 1024 + col];
  float hcur = 0.f;
  stg_coh_u32(exch + b * 1024 + col,
              ((unsigned)(u16)f2bf(h0[b * 1024 + col]) << 16) | 1u);
  __syncthreads();    // Whs ready for bfr hoist

  // --- hoist B-fragments (constant across t)
  bf16x8 bfr[2][4];
  #pragma unroll
  for (int ct = 0; ct < 2; ++ct)
    #pragma unroll
    for (int kk = 0; kk < 4; ++kk) {
      int j2  = ct * 16 + jl;
      int grp = wave * 16 + kk * 4 + kq;
      bfr[ct][kk] = *(const bf16x8*)&Whs[(j2 * 128 + (grp ^ (j2 & 7))) * 8];
    }

  const int ct_o = cp >> 4;
  const int j16  = cp & 15;
  const int lred = ((bp >> 2) << 4) | j16;
  const int rred = bp & 3;
  const size_t obase = (size_t)b * (S_ * H_) + col;
  const unsigned* aptr = exch + (size_t)(bg * 16 + jl) * 1024 + wave * 128 + kq * 8;

  float xz = out[obase];   // prefetch xz for t=0

  for (int t = 0; t < S_; ++t) {
    const unsigned* srcb = aptr + (size_t)(t & 1) * EXN32;
    const unsigned etag  = (unsigned)(t + 1);

    // ---- spin on self-validating fragment loads (8 x dwordx4, sc0sc1)
    u32x4 L0, L1, L2, L3, L4, L5, L6, L7;
#define LDC(dst, off) asm volatile( \
    "global_load_dwordx4 %0, %1, off offset:" off " sc0 sc1" \
    : "=v"(dst) : "v"(srcb) : "memory")
    for (;;) {
      LDC(L0, "0");   LDC(L1, "16");
      LDC(L2, "128"); LDC(L3, "144");
      LDC(L4, "256"); LDC(L5, "272");
      LDC(L6, "384"); LDC(L7, "400");
      asm volatile("s_waitcnt vmcnt(0)" ::: "memory");
      __builtin_amdgcn_sched_barrier(0);
      unsigned acc;
      acc  = (L0[0] ^ etag) | (L0[1] ^ etag) | (L0[2] ^ etag) | (L0[3] ^ etag);
      acc |= (L1[0] ^ etag) | (L1[1] ^ etag) | (L1[2] ^ etag) | (L1[3] ^ etag);
      acc |= (L2[0] ^ etag) | (L2[1] ^ etag) | (L2[2] ^ etag) | (L2[3] ^ etag);
      acc |= (L3[0] ^ etag) | (L3[1] ^ etag) | (L3[2] ^ etag) | (L3[3] ^ etag);
      acc |= (L4[0] ^ etag) | (L4[1] ^ etag) | (L4[2] ^ etag) | (L4[3] ^ etag);
      acc |= (L5[0] ^ etag) | (L5[1] ^ etag) | (L5[2] ^ etag) | (L5[3] ^ etag);
      acc |= (L6[0] ^ etag) | (L6[1] ^ etag) | (L6[2] ^ etag) | (L6[3] ^ etag);
      acc |= (L7[0] ^ etag) | (L7[1] ^ etag) | (L7[2] ^ etag) | (L7[3] ^ etag);
      if (__all((acc & 0xffffu) == 0u)) break;
    }
#undef LDC

    // ---- unpack + MFMA partials into parity zred
    bf16x8 afr[4];
    afr[0] = mk_frag(L0, L1);
    afr[1] = mk_frag(L2, L3);
    afr[2] = mk_frag(L4, L5);
    afr[3] = mk_frag(L6, L7);
    #pragma unroll
    for (int ct = 0; ct < 2; ++ct) {
      f32x4 pacc = {0.f, 0.f, 0.f, 0.f};
      #pragma unroll
      for (int kk = 0; kk < 4; ++kk)
        pacc = __builtin_amdgcn_mfma_f32_16x16x32_bf16(afr[kk], bfr[ct][kk], pacc, 0, 0, 0);
      #pragma unroll
      for (int r = 0; r < 4; ++r)
        zred[t & 1][wave][ct][lane][r] = pacc[r];
    }

    // prefetch next xz (hides a full step of latency)
    const size_t nxi = obase + (size_t)(t + 1 < S_ ? t + 1 : t) * H_;
    float xz_next = out[nxi];

    __syncthreads();   // the ONLY barrier per step

    // ---- owner: reduce 8 waves, gates, publish
    float z = xz;
    #pragma unroll
    for (int w = 0; w < 8; ++w) z += zred[t & 1][w][ct_o][lred][rred];
    float sg  = 1.f / (1.f + __expf(-z));
    float e2z = __expf(2.f * z);
    float tz  = 1.f - 2.f / (e2z + 1.f);
    cst  = sg * (cst + tz);
    float e2c = __expf(2.f * cst);
    float tc  = 1.f - 2.f / (e2c + 1.f);
    hcur = sg * tc;
    stg_coh_u32(exch + (size_t)((t + 1) & 1) * EXN32 + b * 1024 + col,
                ((unsigned)(u16)f2bf(hcur) << 16) | (unsigned)(t + 2));
    out[obase + (size_t)t * H_] = hcur;   // plain cached store, off-path
    xz = xz_next;
  }

  // ---- hn, cn
  const size_t OFS = (size_t)B_ * S_ * H_;
  out[OFS + b * 1024 + col] = hcur;
  out[OFS + (size_t)B_ * H_ + b * 1024 + col] = cst;
}

// ============================================================================
extern "C" void kernel_launch(void* const* d_in, const int* in_sizes, int n_in,
                              void* d_out, int out_size, void* d_ws, size_t ws_size,
                              hipStream_t stream) {
  const float* x    = (const float*)d_in[0];
  const float* h0   = (const float*)d_in[1];
  const float* c0   = (const float*)d_in[2];
  const float* W    = (const float*)d_in[3];
  const float* bias = (const float*)d_in[4];
  float* out = (float*)d_out;

  unsigned* exch = (unsigned*)d_ws;   // 2 x 128 KB ping-pong, packed h|tag
  // zero tags so no stale-version false positives across graph replays
  hipMemsetAsync(exch, 0, 2 * EXN32 * sizeof(unsigned), stream);

  xz_gemm<<<dim3(8, 256), 256, 0, stream>>>(x, W, bias, out);
  lstm_rec<<<dim3(NWG), 512, 0, stream>>>(W, h0, c0, out, exch);
}